// Round 1
// baseline (764.047 us; speedup 1.0000x reference)
//
#include <hip/hip_runtime.h>
#include <math.h>

// Problem constants (fixed by reference): B=1024, NMAX=128, D=256, NUM=4
#define BB   1024
#define DD   256
#define LOGD 5.5451774444795624753f   // log(256)

__device__ __forceinline__ float wave_max(float v){
  #pragma unroll
  for (int off=32; off>0; off>>=1) v = fmaxf(v, __shfl_xor(v, off, 64));
  return v;
}
__device__ __forceinline__ float wave_sum(float v){
  #pragma unroll
  for (int off=32; off>0; off>>=1) v += __shfl_xor(v, off, 64);
  return v;
}
__device__ __forceinline__ float fast_tanh(float x){
  // tanh(x) = 1 - 2/(exp(2x)+1); saturates correctly for large |x|
  return 1.0f - 2.0f/(__expf(2.0f*x)+1.0f);
}

// ---- K1: segment bounds via binary search (batch is sorted) ----
__global__ void k_bounds(const int* __restrict__ batch, int T, int* __restrict__ starts){
  int b = blockIdx.x*blockDim.x + threadIdx.x;
  if (b > BB) return;
  int lo = 0, hi = T;
  while (lo < hi){ int mid = (lo+hi)>>1; if (batch[mid] < b) lo = mid+1; else hi = mid; }
  starts[b] = lo;
}

// ---- K1b: scalar parameter chain (softplus + closed-form log_mu/z1 recurrence) ----
// P layout: [0..3]=r_k  [4..7]=1/(b1+r)  [8..11]=1/(b2+r)  [12..15]=log_mu entering iter k
//           [16..19]=b3 [20..23]=1/(b3+r)
__global__ void k_params(const float* __restrict__ rho, const float* __restrict__ a1,
                         const float* __restrict__ a2, const float* __restrict__ a3,
                         float* __restrict__ P){
  if (threadIdx.x != 0 || blockIdx.x != 0) return;
  float lm = -LOGD, z1 = 0.f;
  for (int k=0;k<4;k++){
    float r  = log1pf(expf(rho[k]));
    float b1 = log1pf(expf(a1[k]));
    float b2 = log1pf(expf(a2[k]));
    float b3 = log1pf(expf(a3[k]));
    P[k]    = r;
    P[4+k]  = 1.f/(b1+r);
    P[8+k]  = 1.f/(b2+r);
    P[12+k] = lm;              // mu used by S-update of iteration k (pre-update value)
    P[16+k] = b3;
    P[20+k] = 1.f/(b3+r);
    float lmn = (b3*(-LOGD) - z1 + r*lm)/(b3+r);
    z1 += r*(expf(lmn)-expf(lm));
    lm = lmn;
  }
}

// ---- K2: fused MLP  logits[t] = tanh(x[t]@W1^T) @ W2 ----
// fp32 tiled GEMM, 128(M) x 128(N) block tile, K-tiles of 32, 8x8 micro-tile.
#define TS 132   // padded LDS stride (132*4=528 B, 16B-aligned rows)
__global__ __launch_bounds__(256, 2) void k_mlp(
    const float* __restrict__ x, const float* __restrict__ W1,
    const float* __restrict__ W2, float* __restrict__ logits, int T)
{
  __shared__ float Xs[32*TS];
  __shared__ float Ws[32*TS];
  __shared__ float lred[128];
  const int bx = blockIdx.x;        // row tile
  const int by = blockIdx.y;        // j tile (0..3)
  const int tid = threadIdx.x;
  const int tm = tid & 15, tj = tid >> 4;
  const int kq = tid & 7, lrow = tid >> 3;
  float acc[8][8];
  #pragma unroll
  for (int i=0;i<8;i++)
    #pragma unroll
    for (int j=0;j<8;j++) acc[i][j]=0.f;

  for (int kt=0; kt<8; kt++){
    const int k0 = kt*32;
    #pragma unroll
    for (int p=0;p<4;p++){
      const int rloc = lrow + p*32;
      const int grow = bx*128 + rloc;
      float4 v = make_float4(0.f,0.f,0.f,0.f);
      if (grow < T) v = *(const float4*)(x + (size_t)grow*DD + k0 + kq*4);
      Xs[(kq*4+0)*TS + rloc] = v.x;
      Xs[(kq*4+1)*TS + rloc] = v.y;
      Xs[(kq*4+2)*TS + rloc] = v.z;
      Xs[(kq*4+3)*TS + rloc] = v.w;
      const int gj = by*128 + rloc;   // always < 512
      float4 wv = *(const float4*)(W1 + (size_t)gj*DD + k0 + kq*4);
      Ws[(kq*4+0)*TS + rloc] = wv.x;
      Ws[(kq*4+1)*TS + rloc] = wv.y;
      Ws[(kq*4+2)*TS + rloc] = wv.z;
      Ws[(kq*4+3)*TS + rloc] = wv.w;
    }
    __syncthreads();
    #pragma unroll
    for (int kk=0; kk<32; kk++){
      const float4 a0 = *(const float4*)&Xs[kk*TS + tm*8];
      const float4 a1 = *(const float4*)&Xs[kk*TS + tm*8 + 4];
      const float4 b0 = *(const float4*)&Ws[kk*TS + tj*8];
      const float4 b1 = *(const float4*)&Ws[kk*TS + tj*8 + 4];
      const float av[8] = {a0.x,a0.y,a0.z,a0.w,a1.x,a1.y,a1.z,a1.w};
      const float bv[8] = {b0.x,b0.y,b0.z,b0.w,b1.x,b1.y,b1.z,b1.w};
      #pragma unroll
      for (int i=0;i<8;i++)
        #pragma unroll
        for (int j=0;j<8;j++)
          acc[i][j] = fmaf(av[i], bv[j], acc[i][j]);
    }
    __syncthreads();
  }
  // epilogue: tanh + dot with W2 segment, reduce partial logits per row
  float w2v[8];
  #pragma unroll
  for (int jj=0;jj<8;jj++) w2v[jj] = W2[by*128 + tj*8 + jj];
  float part[8];
  #pragma unroll
  for (int i=0;i<8;i++){
    float s = 0.f;
    #pragma unroll
    for (int jj=0;jj<8;jj++) s += fast_tanh(acc[i][jj]) * w2v[jj];
    part[i] = s;
  }
  if (tid < 128) lred[tid] = 0.f;
  __syncthreads();
  #pragma unroll
  for (int i=0;i<8;i++) atomicAdd(&lred[tm*8+i], part[i]);
  __syncthreads();
  if (tid < 128){
    const int grow = bx*128 + tid;
    if (grow < T) atomicAdd(logits + grow, lred[tid]);
  }
}

// ---- K3: per-segment softmax -> log(q0 + 1e-8) ----
__global__ void k_seg_softmax(const float* __restrict__ logits, const int* __restrict__ starts,
                              float* __restrict__ lq0)
{
  const int b = blockIdx.x;
  const int start = starts[b], len = starts[b+1]-start;
  const int l = threadIdx.x; // 64 threads = 1 wave
  float v0 = (l      < len) ? logits[start+l]    : -3.0e38f;
  float v1 = (l+64   < len) ? logits[start+l+64] : -3.0e38f;
  float m = wave_max(fmaxf(v0,v1));
  float e0 = (l    < len) ? __expf(v0-m) : 0.f;
  float e1 = (l+64 < len) ? __expf(v1-m) : 0.f;
  float s = wave_sum(e0+e1);
  float inv = 1.f/(s + 1e-16f);
  if (l      < len) lq0[start+l]    = __logf(e0*inv + 1e-8f);
  if (l+64   < len) lq0[start+l+64] = __logf(e1*inv + 1e-8f);
}

// ---- K4: BADMM solver, one block per batch ----
// Layout: wave w owns rows 8w..8w+7; lane l owns cols {l, l+64, l+128, l+192}.
// A (LDS) holds log_s, overwritten with log_t then log_s_new each iteration.
// z lives in registers (8x4 per thread). mu/z1 from P (scalar, batch-independent);
// eta/z2 per-row register recurrences (exact identities, see analysis).
__global__ __launch_bounds__(1024, 4) void k_solver(
    const float* __restrict__ x, const float* __restrict__ lq0,
    const int* __restrict__ starts, const float* __restrict__ P,
    float* __restrict__ out)
{
  __shared__ float A[128*DD];     // 128 KB
  __shared__ float red[16*DD];    // 16 KB
  __shared__ float colv[DD];      // 1 KB
  const int b = blockIdx.x;
  const int start = starts[b];
  const int len = starts[b+1] - start;
  const int tid = threadIdx.x;
  const int w = tid >> 6, l = tid & 63;
  const int n0 = w*8;
  int nv = len - n0; nv = nv < 0 ? 0 : (nv > 8 ? 8 : nv);

  float z[8][4];
  float eta[8], z2r[8], lq[8];
  #pragma unroll
  for (int r=0;r<8;r++){
    #pragma unroll
    for (int j=0;j<4;j++) z[r][j]=0.f;
    z2r[r]=0.f; lq[r]=0.f; eta[r]=0.f;
    if (r < nv){ float v = lq0[start + n0 + r]; lq[r]=v; eta[r]=v; }
  }
  // init A = log_q0 + log_p0
  #pragma unroll
  for (int r=0;r<8;r++){
    if (r < nv){
      const float v = lq[r] - LOGD;
      const int base = (n0+r)*DD + l;
      #pragma unroll
      for (int j=0;j<4;j++) A[base + 64*j] = v;
    }
  }

  for (int k=0;k<3;k++){
    const float rk = P[k], ib1 = P[4+k], ib2 = P[8+k], muk = P[12+k];
    const float b3 = P[16+k], ib3r = P[20+k];
    // ---- P1: T-update (row LSE over D), A: log_s -> log_t ----
    #pragma unroll
    for (int r=0;r<8;r++){
      if (r < nv){
        const int n = n0 + r;
        const float* xp = x + (size_t)(start+n)*DD + l;
        const int base = n*DD + l;
        float y[4];
        #pragma unroll
        for (int j=0;j<4;j++) y[j] = (xp[64*j] - z[r][j] + rk*A[base+64*j]) * ib2;
        float m = fmaxf(fmaxf(y[0],y[1]), fmaxf(y[2],y[3]));
        m = wave_max(m);
        float se = 0.f;
        #pragma unroll
        for (int j=0;j<4;j++) se += __expf(y[j]-m);
        se = wave_sum(se);
        const float lse = m + __logf(se);
        const float e = eta[r];
        #pragma unroll
        for (int j=0;j<4;j++) A[base+64*j] = e + y[j] - lse;
      }
    }
    // ---- P2a: column max of y_s ----
    float mp[4] = {-3.0e38f,-3.0e38f,-3.0e38f,-3.0e38f};
    #pragma unroll
    for (int r=0;r<8;r++){
      if (r < nv){
        const int base = (n0+r)*DD + l;
        #pragma unroll
        for (int j=0;j<4;j++){
          const float ys = (z[r][j] + rk*A[base+64*j]) * ib1;
          mp[j] = fmaxf(mp[j], ys);
        }
      }
    }
    #pragma unroll
    for (int j=0;j<4;j++) red[w*DD + l + 64*j] = mp[j];
    __syncthreads();
    if (tid < DD){
      float m = -3.0e38f;
      #pragma unroll
      for (int ww=0; ww<16; ww++) m = fmaxf(m, red[ww*DD + tid]);
      colv[tid] = m;
    }
    __syncthreads();
    // ---- P2b: column sum-exp ----
    float cm[4];
    #pragma unroll
    for (int j=0;j<4;j++) cm[j] = colv[l + 64*j];
    float sp[4] = {0.f,0.f,0.f,0.f};
    #pragma unroll
    for (int r=0;r<8;r++){
      if (r < nv){
        const int base = (n0+r)*DD + l;
        #pragma unroll
        for (int j=0;j<4;j++){
          const float ys = (z[r][j] + rk*A[base+64*j]) * ib1;
          sp[j] += __expf(ys - cm[j]);
        }
      }
    }
    #pragma unroll
    for (int j=0;j<4;j++) red[w*DD + l + 64*j] = sp[j];
    __syncthreads();
    if (tid < DD){
      float s = 0.f;
      #pragma unroll
      for (int ww=0; ww<16; ww++) s += red[ww*DD + tid];
      colv[tid] = colv[tid] + __logf(s);   // column LSE
    }
    __syncthreads();
    // ---- P3: S-update + dual ascent, A: log_t -> log_s_new ----
    float lsc[4];
    #pragma unroll
    for (int j=0;j<4;j++) lsc[j] = colv[l + 64*j];
    #pragma unroll
    for (int r=0;r<8;r++){
      if (r < nv){
        const int base = (n0+r)*DD + l;
        #pragma unroll
        for (int j=0;j<4;j++){
          const float lt  = A[base+64*j];
          const float ys  = (z[r][j] + rk*lt) * ib1;
          const float lsn = muk + ys - lsc[j];
          const float s = __expf(lsn);
          const float t = __expf(lt);
          z[r][j] += rk*(t - s);
          A[base+64*j] = lsn;
        }
        // eta / z2 recurrence (exact identity: sum_d t = exp(eta_old))
        const float en = (b3*lq[r] - z2r[r] + rk*eta[r]) * ib3r;
        z2r[r] += rk*(__expf(en) - __expf(eta[r]));
        eta[r] = en;
      }
    }
  }
  // ---- k=3: T-update only (returned log_t precedes S-update) + output ----
  {
    const float rk = P[3], ib2 = P[8+3];
    float op[4] = {0.f,0.f,0.f,0.f};
    #pragma unroll
    for (int r=0;r<8;r++){
      if (r < nv){
        const int n = n0 + r;
        const float* xp = x + (size_t)(start+n)*DD + l;
        const int base = n*DD + l;
        float y[4], xv[4];
        #pragma unroll
        for (int j=0;j<4;j++){
          xv[j] = xp[64*j];
          y[j] = (xv[j] - z[r][j] + rk*A[base+64*j]) * ib2;
        }
        float m = fmaxf(fmaxf(y[0],y[1]), fmaxf(y[2],y[3]));
        m = wave_max(m);
        float se = 0.f;
        #pragma unroll
        for (int j=0;j<4;j++) se += __expf(y[j]-m);
        se = wave_sum(se);
        const float lse = m + __logf(se);
        const float e = eta[r];
        #pragma unroll
        for (int j=0;j<4;j++){
          const float t = __expf(e + y[j] - lse);
          op[j] += xv[j]*t;
        }
      }
    }
    #pragma unroll
    for (int j=0;j<4;j++) red[w*DD + l + 64*j] = op[j];
    __syncthreads();
    if (tid < DD){
      float s = 0.f;
      #pragma unroll
      for (int ww=0; ww<16; ww++) s += red[ww*DD + tid];
      out[(size_t)b*DD + tid] = 256.0f * s;   // frot = D * x * t, summed over n
    }
  }
}

extern "C" void kernel_launch(void* const* d_in, const int* in_sizes, int n_in,
                              void* d_out, int out_size, void* d_ws, size_t ws_size,
                              hipStream_t stream) {
  const float* x    = (const float*)d_in[0];
  const int*   batch= (const int*)d_in[1];
  const float* W1   = (const float*)d_in[2];
  const float* W2   = (const float*)d_in[3];
  const float* rho  = (const float*)d_in[4];
  const float* a1   = (const float*)d_in[5];
  const float* a2   = (const float*)d_in[6];
  const float* a3   = (const float*)d_in[7];
  float* out = (float*)d_out;
  const int T = in_sizes[1];   // total ragged rows

  // workspace layout (all re-derived every call; ws is poisoned between calls)
  float* logits = (float*)d_ws;            // T floats
  float* lq0    = logits + T;              // T floats
  int*   starts = (int*)(lq0 + T);         // B+1 ints
  float* P      = (float*)(starts + 1028); // 24 floats (padded for alignment)

  k_bounds<<<dim3((BB+1+255)/256), 256, 0, stream>>>(batch, T, starts);
  k_params<<<1, 64, 0, stream>>>(rho, a1, a2, a3, P);
  hipMemsetAsync(logits, 0, (size_t)T*sizeof(float), stream);
  k_mlp<<<dim3((T+127)/128, 4), 256, 0, stream>>>(x, W1, W2, logits, T);
  k_seg_softmax<<<BB, 64, 0, stream>>>(logits, starts, lq0);
  k_solver<<<BB, 1024, 0, stream>>>(x, lq0, starts, P, out);
}

// Round 2
// 510.012 us; speedup vs baseline: 1.4981x; 1.4981x over previous
//
#include <hip/hip_runtime.h>
#include <math.h>

// Problem constants (fixed by reference): B=1024, NMAX=128, D=256, NUM=4
#define BB   1024
#define DD   256
#define LOGD 5.5451774444795624753f   // log(256)

typedef __attribute__((ext_vector_type(8))) short short8;   // 8 bf16 = 4 VGPRs
typedef __attribute__((ext_vector_type(4))) float f32x4;    // MFMA acc

__device__ __forceinline__ float wave_max(float v){
  #pragma unroll
  for (int off=32; off>0; off>>=1) v = fmaxf(v, __shfl_xor(v, off, 64));
  return v;
}
__device__ __forceinline__ float wave_sum(float v){
  #pragma unroll
  for (int off=32; off>0; off>>=1) v += __shfl_xor(v, off, 64);
  return v;
}
__device__ __forceinline__ float fast_tanh(float x){
  return 1.0f - 2.0f/(__expf(2.0f*x)+1.0f);
}
__device__ __forceinline__ unsigned short f2bf(float f){
  unsigned int u = __float_as_uint(f);
  unsigned int r = u + 0x7FFFu + ((u >> 16) & 1u);   // RNE
  return (unsigned short)(r >> 16);
}

// ---- K1: segment bounds via binary search (batch is sorted) ----
__global__ void k_bounds(const int* __restrict__ batch, int T, int* __restrict__ starts){
  int b = blockIdx.x*blockDim.x + threadIdx.x;
  if (b > BB) return;
  int lo = 0, hi = T;
  while (lo < hi){ int mid = (lo+hi)>>1; if (batch[mid] < b) lo = mid+1; else hi = mid; }
  starts[b] = lo;
}

// ---- K1b: scalar parameter chain (softplus + closed-form log_mu/z1 recurrence) ----
__global__ void k_params(const float* __restrict__ rho, const float* __restrict__ a1,
                         const float* __restrict__ a2, const float* __restrict__ a3,
                         float* __restrict__ P){
  if (threadIdx.x != 0 || blockIdx.x != 0) return;
  float lm = -LOGD, z1 = 0.f;
  for (int k=0;k<4;k++){
    float r  = log1pf(expf(rho[k]));
    float b1 = log1pf(expf(a1[k]));
    float b2 = log1pf(expf(a2[k]));
    float b3 = log1pf(expf(a3[k]));
    P[k]    = r;
    P[4+k]  = 1.f/(b1+r);
    P[8+k]  = 1.f/(b2+r);
    P[12+k] = lm;              // mu used by S-update of iteration k (pre-update value)
    P[16+k] = b3;
    P[20+k] = 1.f/(b3+r);
    float lmn = (b3*(-LOGD) - z1 + r*lm)/(b3+r);
    z1 += r*(expf(lmn)-expf(lm));
    lm = lmn;
  }
}

// ---- K2: fused MLP via bf16 MFMA ----
// logits[t] = tanh(x[t]@W1^T) @ W2^T. Block: 512 thr (8 waves), tile M=128 x
// N=128 (grid.y=4 over 512 hidden), K=256 fully resident in LDS.
// LDS rows padded to 264 bf16 (528B = 4-bank row stride -> b128 frag reads are
// perfectly bank-balanced: 8 lanes per 4-bank group, the hardware minimum).
// Wave tile 64x32: 4(M) x 2(N) mfma_f32_16x16x32_bf16 accumulators.
#define LPAD 264
__global__ __launch_bounds__(512, 1) void k_mlp(
    const float* __restrict__ x, const float* __restrict__ W1,
    const float* __restrict__ W2, float* __restrict__ logits, int T)
{
  __shared__ unsigned short Xs[128*LPAD];   // 67584 B
  __shared__ unsigned short Ws[128*LPAD];   // 67584 B
  __shared__ float lred[128];
  const int bx = blockIdx.x;   // row tile
  const int by = blockIdx.y;   // hidden tile (0..3)
  const int tid = threadIdx.x;

  if (tid < 128) lred[tid] = 0.f;

  // stage + convert: each iteration loads one float4 (4 fp32 -> 4 bf16) per array
  #pragma unroll
  for (int i=0;i<16;i++){
    const int t = i*512 + tid;        // 0..8191
    const int row = t >> 6;           // 0..127
    const int c   = t & 63;           // float4 chunk
    const int grow = bx*128 + row;
    float4 v = make_float4(0.f,0.f,0.f,0.f);
    if (grow < T) v = *(const float4*)(x + (size_t)grow*DD + c*4);
    ushort4 pv = make_ushort4(f2bf(v.x), f2bf(v.y), f2bf(v.z), f2bf(v.w));
    *(ushort4*)&Xs[row*LPAD + c*4] = pv;
    const float4 wv = *(const float4*)(W1 + (size_t)(by*128+row)*DD + c*4);
    ushort4 pw = make_ushort4(f2bf(wv.x), f2bf(wv.y), f2bf(wv.z), f2bf(wv.w));
    *(ushort4*)&Ws[row*LPAD + c*4] = pw;
  }
  __syncthreads();

  const int l   = tid & 63;
  const int w   = tid >> 6;           // wave 0..7
  const int wm  = w >> 2;             // 0..1 (M half)
  const int wn  = w & 3;              // 0..3 (N quarter)
  const int lr  = l & 15;
  const int quad= l >> 4;

  f32x4 acc[4][2];
  #pragma unroll
  for (int mi=0;mi<4;mi++)
    #pragma unroll
    for (int ni=0;ni<2;ni++) acc[mi][ni] = (f32x4){0.f,0.f,0.f,0.f};

  #pragma unroll
  for (int ks=0; ks<8; ks++){
    short8 afr[4], bfr[2];
    #pragma unroll
    for (int mi=0;mi<4;mi++)
      afr[mi] = *(const short8*)&Xs[(wm*64 + mi*16 + lr)*LPAD + ks*32 + quad*8];
    #pragma unroll
    for (int ni=0;ni<2;ni++)
      bfr[ni] = *(const short8*)&Ws[(wn*32 + ni*16 + lr)*LPAD + ks*32 + quad*8];
    #pragma unroll
    for (int mi=0;mi<4;mi++)
      #pragma unroll
      for (int ni=0;ni<2;ni++)
        acc[mi][ni] = __builtin_amdgcn_mfma_f32_16x16x32_bf16(afr[mi], bfr[ni], acc[mi][ni], 0, 0, 0);
  }

  // epilogue: tanh + dot W2 + reduce over the 16-lane column group
  float w2v[2];
  #pragma unroll
  for (int ni=0;ni<2;ni++) w2v[ni] = W2[by*128 + wn*32 + ni*16 + lr];
  #pragma unroll
  for (int mi=0;mi<4;mi++){
    float p[4];
    #pragma unroll
    for (int v=0; v<4; v++){
      p[v] = fast_tanh(acc[mi][0][v])*w2v[0] + fast_tanh(acc[mi][1][v])*w2v[1];
      #pragma unroll
      for (int off=1; off<16; off<<=1) p[v] += __shfl_xor(p[v], off, 64);
    }
    if (lr == 0){
      #pragma unroll
      for (int v=0; v<4; v++)
        atomicAdd(&lred[wm*64 + mi*16 + quad*4 + v], p[v]);
    }
  }
  __syncthreads();
  if (tid < 128){
    const int grow = bx*128 + tid;
    if (grow < T) atomicAdd(logits + grow, lred[tid]);
  }
}

// ---- K3: per-segment softmax -> log(q0 + 1e-8) ----
__global__ void k_seg_softmax(const float* __restrict__ logits, const int* __restrict__ starts,
                              float* __restrict__ lq0)
{
  const int b = blockIdx.x;
  const int start = starts[b], len = starts[b+1]-start;
  const int l = threadIdx.x; // 64 threads = 1 wave
  float v0 = (l      < len) ? logits[start+l]    : -3.0e38f;
  float v1 = (l+64   < len) ? logits[start+l+64] : -3.0e38f;
  float m = wave_max(fmaxf(v0,v1));
  float e0 = (l    < len) ? __expf(v0-m) : 0.f;
  float e1 = (l+64 < len) ? __expf(v1-m) : 0.f;
  float s = wave_sum(e0+e1);
  float inv = 1.f/(s + 1e-16f);
  if (l      < len) lq0[start+l]    = __logf(e0*inv + 1e-8f);
  if (l+64   < len) lq0[start+l+64] = __logf(e1*inv + 1e-8f);
}

// ---- K4: BADMM solver, one block per batch ----
__global__ __launch_bounds__(1024, 4) void k_solver(
    const float* __restrict__ x, const float* __restrict__ lq0,
    const int* __restrict__ starts, const float* __restrict__ P,
    float* __restrict__ out)
{
  __shared__ float A[128*DD];     // 128 KB
  __shared__ float red[16*DD];    // 16 KB
  __shared__ float colv[DD];      // 1 KB
  const int b = blockIdx.x;
  const int start = starts[b];
  const int len = starts[b+1] - start;
  const int tid = threadIdx.x;
  const int w = tid >> 6, l = tid & 63;
  const int n0 = w*8;
  int nv = len - n0; nv = nv < 0 ? 0 : (nv > 8 ? 8 : nv);

  float z[8][4];
  float eta[8], z2r[8], lq[8];
  #pragma unroll
  for (int r=0;r<8;r++){
    #pragma unroll
    for (int j=0;j<4;j++) z[r][j]=0.f;
    z2r[r]=0.f; lq[r]=0.f; eta[r]=0.f;
    if (r < nv){ float v = lq0[start + n0 + r]; lq[r]=v; eta[r]=v; }
  }
  #pragma unroll
  for (int r=0;r<8;r++){
    if (r < nv){
      const float v = lq[r] - LOGD;
      const int base = (n0+r)*DD + l;
      #pragma unroll
      for (int j=0;j<4;j++) A[base + 64*j] = v;
    }
  }

  for (int k=0;k<3;k++){
    const float rk = P[k], ib1 = P[4+k], ib2 = P[8+k], muk = P[12+k];
    const float b3 = P[16+k], ib3r = P[20+k];
    // ---- P1: T-update (row LSE over D), A: log_s -> log_t ----
    #pragma unroll
    for (int r=0;r<8;r++){
      if (r < nv){
        const int n = n0 + r;
        const float* xp = x + (size_t)(start+n)*DD + l;
        const int base = n*DD + l;
        float y[4];
        #pragma unroll
        for (int j=0;j<4;j++) y[j] = (xp[64*j] - z[r][j] + rk*A[base+64*j]) * ib2;
        float m = fmaxf(fmaxf(y[0],y[1]), fmaxf(y[2],y[3]));
        m = wave_max(m);
        float se = 0.f;
        #pragma unroll
        for (int j=0;j<4;j++) se += __expf(y[j]-m);
        se = wave_sum(se);
        const float lse = m + __logf(se);
        const float e = eta[r];
        #pragma unroll
        for (int j=0;j<4;j++) A[base+64*j] = e + y[j] - lse;
      }
    }
    // ---- P2a: column max of y_s ----
    float mp[4] = {-3.0e38f,-3.0e38f,-3.0e38f,-3.0e38f};
    #pragma unroll
    for (int r=0;r<8;r++){
      if (r < nv){
        const int base = (n0+r)*DD + l;
        #pragma unroll
        for (int j=0;j<4;j++){
          const float ys = (z[r][j] + rk*A[base+64*j]) * ib1;
          mp[j] = fmaxf(mp[j], ys);
        }
      }
    }
    #pragma unroll
    for (int j=0;j<4;j++) red[w*DD + l + 64*j] = mp[j];
    __syncthreads();
    if (tid < DD){
      float m = -3.0e38f;
      #pragma unroll
      for (int ww=0; ww<16; ww++) m = fmaxf(m, red[ww*DD + tid]);
      colv[tid] = m;
    }
    __syncthreads();
    // ---- P2b: column sum-exp ----
    float cm[4];
    #pragma unroll
    for (int j=0;j<4;j++) cm[j] = colv[l + 64*j];
    float sp[4] = {0.f,0.f,0.f,0.f};
    #pragma unroll
    for (int r=0;r<8;r++){
      if (r < nv){
        const int base = (n0+r)*DD + l;
        #pragma unroll
        for (int j=0;j<4;j++){
          const float ys = (z[r][j] + rk*A[base+64*j]) * ib1;
          sp[j] += __expf(ys - cm[j]);
        }
      }
    }
    #pragma unroll
    for (int j=0;j<4;j++) red[w*DD + l + 64*j] = sp[j];
    __syncthreads();
    if (tid < DD){
      float s = 0.f;
      #pragma unroll
      for (int ww=0; ww<16; ww++) s += red[ww*DD + tid];
      colv[tid] = colv[tid] + __logf(s);   // column LSE
    }
    __syncthreads();
    // ---- P3: S-update + dual ascent, A: log_t -> log_s_new ----
    float lsc[4];
    #pragma unroll
    for (int j=0;j<4;j++) lsc[j] = colv[l + 64*j];
    #pragma unroll
    for (int r=0;r<8;r++){
      if (r < nv){
        const int base = (n0+r)*DD + l;
        #pragma unroll
        for (int j=0;j<4;j++){
          const float lt  = A[base+64*j];
          const float ys  = (z[r][j] + rk*lt) * ib1;
          const float lsn = muk + ys - lsc[j];
          const float s = __expf(lsn);
          const float t = __expf(lt);
          z[r][j] += rk*(t - s);
          A[base+64*j] = lsn;
        }
        const float en = (b3*lq[r] - z2r[r] + rk*eta[r]) * ib3r;
        z2r[r] += rk*(__expf(en) - __expf(eta[r]));
        eta[r] = en;
      }
    }
  }
  // ---- k=3: T-update only + output ----
  {
    const float rk = P[3], ib2 = P[8+3];
    float op[4] = {0.f,0.f,0.f,0.f};
    #pragma unroll
    for (int r=0;r<8;r++){
      if (r < nv){
        const int n = n0 + r;
        const float* xp = x + (size_t)(start+n)*DD + l;
        const int base = n*DD + l;
        float y[4], xv[4];
        #pragma unroll
        for (int j=0;j<4;j++){
          xv[j] = xp[64*j];
          y[j] = (xv[j] - z[r][j] + rk*A[base+64*j]) * ib2;
        }
        float m = fmaxf(fmaxf(y[0],y[1]), fmaxf(y[2],y[3]));
        m = wave_max(m);
        float se = 0.f;
        #pragma unroll
        for (int j=0;j<4;j++) se += __expf(y[j]-m);
        se = wave_sum(se);
        const float lse = m + __logf(se);
        const float e = eta[r];
        #pragma unroll
        for (int j=0;j<4;j++){
          const float t = __expf(e + y[j] - lse);
          op[j] += xv[j]*t;
        }
      }
    }
    #pragma unroll
    for (int j=0;j<4;j++) red[w*DD + l + 64*j] = op[j];
    __syncthreads();
    if (tid < DD){
      float s = 0.f;
      #pragma unroll
      for (int ww=0; ww<16; ww++) s += red[ww*DD + tid];
      out[(size_t)b*DD + tid] = 256.0f * s;
    }
  }
}

extern "C" void kernel_launch(void* const* d_in, const int* in_sizes, int n_in,
                              void* d_out, int out_size, void* d_ws, size_t ws_size,
                              hipStream_t stream) {
  const float* x    = (const float*)d_in[0];
  const int*   batch= (const int*)d_in[1];
  const float* W1   = (const float*)d_in[2];
  const float* W2   = (const float*)d_in[3];
  const float* rho  = (const float*)d_in[4];
  const float* a1   = (const float*)d_in[5];
  const float* a2   = (const float*)d_in[6];
  const float* a3   = (const float*)d_in[7];
  float* out = (float*)d_out;
  const int T = in_sizes[1];   // total ragged rows

  float* logits = (float*)d_ws;            // T floats
  float* lq0    = logits + T;              // T floats
  int*   starts = (int*)(lq0 + T);         // B+1 ints
  float* P      = (float*)(starts + 1028); // 24 floats

  k_bounds<<<dim3((BB+1+255)/256), 256, 0, stream>>>(batch, T, starts);
  k_params<<<1, 64, 0, stream>>>(rho, a1, a2, a3, P);
  hipMemsetAsync(logits, 0, (size_t)T*sizeof(float), stream);
  k_mlp<<<dim3((T+127)/128, 4), 512, 0, stream>>>(x, W1, W2, logits, T);
  k_seg_softmax<<<BB, 64, 0, stream>>>(logits, starts, lq0);
  k_solver<<<BB, 1024, 0, stream>>>(x, lq0, starts, P, out);
}